// Round 16
// baseline (184.691 us; speedup 1.0000x reference)
//
#include <hip/hip_runtime.h>

typedef unsigned short u16;
typedef __attribute__((ext_vector_type(8))) short bf16x8;
typedef __attribute__((ext_vector_type(4))) float f32x4;
typedef __attribute__((ext_vector_type(16))) float f32x16;
typedef __attribute__((ext_vector_type(4))) unsigned u32x4;

#define B_ 2
#define N_ 2048
#define C_ 1024
#define H_ 16
#define D_ 64
#define M_ (B_ * N_)  // 4096

// 0.125 * log2(e): fold the 1/sqrt(D) scale and exp->exp2 conversion into Q.
#define QSCALE 0.18033688011114336f

#define EXP2R(x) __builtin_amdgcn_exp2f(x)

__device__ __forceinline__ u16 f2bf(float f) {
    union { float f; unsigned u; } x; x.f = f;
    return (u16)((x.u + 0x8000u) >> 16);
}
__device__ __forceinline__ unsigned pack2bf(float a, float b) {
    union { float f; unsigned u; } x, y; x.f = a; y.f = b;
    return __builtin_amdgcn_perm(y.u + 0x8000u, x.u + 0x8000u, 0x07060302);
}
// single-op pack (RTNE), verified correct in r6
__device__ __forceinline__ unsigned cvtpk2bf(float a, float b) {
    unsigned r;
    asm("v_cvt_pk_bf16_f32 %0, %1, %2" : "=v"(r) : "v"(a), "v"(b));
    return r;
}

__device__ __forceinline__ void async_copy16(const void* gsrc, void* ldst) {
    __builtin_amdgcn_global_load_lds(
        (__attribute__((address_space(1))) void*)gsrc,
        (__attribute__((address_space(3))) void*)ldst,
        16, 0, 0);
}

// ---------------- fused cast fp32 -> bf16 (x, w_qkv, w_proj in one launch) ----------------
__global__ void cast3_kernel(const float* __restrict__ x, const float* __restrict__ wq,
                             const float* __restrict__ wp, u16* __restrict__ xo,
                             u16* __restrict__ wqo, u16* __restrict__ wpo) {
    int b = blockIdx.x;
    const float* s; u16* d;
    if (b < 4096)      { s = x;  d = xo;  }
    else if (b < 7168) { s = wq; d = wqo; b -= 4096; }
    else               { s = wp; d = wpo; b -= 7168; }
    int i = (b * 256 + threadIdx.x) * 4;
    const float4 v = *(const float4*)(s + i);
    uint2 o;
    o.x = pack2bf(v.x, v.y);
    o.y = pack2bf(v.z, v.w);
    *(uint2*)(d + i) = o;
}

// ---------------- gemm0: 8-phase 256x256 schedule (r11, verified WAR-safe) ----------------
// C = A(x_bf [4096,1024]) * B(wqkv_bf [3072,1024])^T, scatter epilogue into q/k/vt.
// grid 192 (16x12), 512 thr (8 waves, 2M x 4N), LDS 128 KB = 2 regions x 4 half-tile slots
// {Ah0,Ah1,Bh0,Bh1} of [128][64] bf16, XOR-swizzled (source (lc7^lr3), read ^l7).
// Ledger: A slots read in ph1+ph3 -> Ah0 stages at ph4/ph8; B slots read ph1+ph2 -> Bh0 at
// ph3/ph7, Bh1 at ph4/ph8. vmcnt(6) at ph4/ph8 completes the next tile before its reads.
__global__ __launch_bounds__(512, 2) void gemm_qkv8(
    const u16* __restrict__ A, const u16* __restrict__ Bm,
    u16* __restrict__ qo, u16* __restrict__ ko, u16* __restrict__ vt) {
    __shared__ u16 L[2][4][8192];  // [region][slot][128*64]
    const int tid = threadIdx.x, lane = tid & 63, w = tid >> 6;  // 8 waves
    const int wm = w >> 2, wn = w & 3;
    const int q16 = lane >> 4, l15 = lane & 15, l7 = lane & 7;
    const int lr3 = lane >> 3, lc7 = lane & 7;
    const int sbid = (blockIdx.x & 7) * 24 + (blockIdx.x >> 3);  // XCD swizzle (192%8==0)
    const int bx = sbid % 12, by = sbid / 12;
    const int m0 = by * 256, n0 = bx * 256;
    const int cswz8 = (lc7 ^ lr3) * 8;

    auto stageHT = [&](int t, int isB, int h) {  // one 16KB half-tile, 2 loads/thread
        if (t > 15) return;
        const u16* src = isB ? Bm : A;
        int base_row = (isB ? n0 : m0) + h * 128;
#pragma unroll
        for (int i = 0; i < 2; ++i) {
            int c = w * 2 + i;  // 1KB chunk 0..15 (8 rows x 128B)
            async_copy16(src + (size_t)(base_row + c * 8 + lr3) * 1024 + t * 64 + cswz8,
                         (char*)L + ((t & 1) * 4 + isB * 2 + h) * 16384 + c * 1024);
        }
    };

    // prologue: tile0 (4 halves) + tile1 (3 halves); drain to 3 HT; barrier.
    stageHT(0, 0, 0); stageHT(0, 1, 0); stageHT(0, 1, 1); stageHT(0, 0, 1);
    stageHT(1, 0, 0); stageHT(1, 1, 0); stageHT(1, 1, 1);
    asm volatile("s_waitcnt vmcnt(6)" ::: "memory");
    __builtin_amdgcn_s_barrier();

    f32x4 acc[8][4] = {};
    const int aRow = l15 * 64;
    const int colsw0 = (q16 ^ l7) * 8, colsw1 = ((4 + q16) ^ l7) * 8;
    const u16* LA[2] = { &L[0][wm][0], &L[1][wm][0] };
    const u16* LB[2] = { &L[0][2 + (wn >> 1)][0], &L[1][2 + (wn >> 1)][0] };
    const int bOff = (wn & 1) * 4096;

    bf16x8 Af[4][2], Bf0[2][2], Bf1[2][2];

    auto readA = [&](int P, int mh) {
#pragma unroll
        for (int i = 0; i < 4; ++i) {
            Af[i][0] = *(const bf16x8*)(LA[P] + (mh * 64 + i * 16) * 64 + aRow + colsw0);
            Af[i][1] = *(const bf16x8*)(LA[P] + (mh * 64 + i * 16) * 64 + aRow + colsw1);
        }
    };
    auto readB = [&](int P, int nh, bf16x8 (*Bf)[2]) {
#pragma unroll
        for (int j = 0; j < 2; ++j) {
            Bf[j][0] = *(const bf16x8*)(LB[P] + bOff + (nh * 32 + j * 16) * 64 + aRow + colsw0);
            Bf[j][1] = *(const bf16x8*)(LB[P] + bOff + (nh * 32 + j * 16) * 64 + aRow + colsw1);
        }
    };
    auto mfma16 = [&](int mh, int nh, bf16x8 (*Bf)[2]) {
        __builtin_amdgcn_s_setprio(1);
#pragma unroll
        for (int i = 0; i < 4; ++i)
#pragma unroll
            for (int j = 0; j < 2; ++j)
#pragma unroll
                for (int ks = 0; ks < 2; ++ks)
                    acc[mh * 4 + i][nh * 2 + j] = __builtin_amdgcn_mfma_f32_16x16x32_bf16(
                        Af[i][ks], Bf[j][ks], acc[mh * 4 + i][nh * 2 + j], 0, 0, 0);
        __builtin_amdgcn_s_setprio(0);
    };

    for (int it = 0; it < 8; ++it) {
        const int T = 2 * it;
        readA(0, 0); readB(0, 0, Bf0); stageHT(T + 1, 0, 1);
        __builtin_amdgcn_s_barrier();
        mfma16(0, 0, Bf0);
        __builtin_amdgcn_s_barrier();
        readB(0, 1, Bf1);
        __builtin_amdgcn_s_barrier();
        mfma16(0, 1, Bf1);
        __builtin_amdgcn_s_barrier();
        readA(0, 1); stageHT(T + 2, 1, 0);
        __builtin_amdgcn_s_barrier();
        mfma16(1, 1, Bf1);
        __builtin_amdgcn_s_barrier();
        stageHT(T + 2, 1, 1); stageHT(T + 2, 0, 0);
        __builtin_amdgcn_s_barrier();
        mfma16(1, 0, Bf0);
        if (it < 7) { asm volatile("s_waitcnt vmcnt(6)" ::: "memory"); }
        else        { asm volatile("s_waitcnt vmcnt(0)" ::: "memory"); }
        __builtin_amdgcn_s_barrier();
        readA(1, 0); readB(1, 0, Bf0); stageHT(T + 2, 0, 1);
        __builtin_amdgcn_s_barrier();
        mfma16(0, 0, Bf0);
        __builtin_amdgcn_s_barrier();
        readB(1, 1, Bf1);
        __builtin_amdgcn_s_barrier();
        mfma16(0, 1, Bf1);
        __builtin_amdgcn_s_barrier();
        readA(1, 1); stageHT(T + 3, 1, 0);
        __builtin_amdgcn_s_barrier();
        mfma16(1, 1, Bf1);
        __builtin_amdgcn_s_barrier();
        stageHT(T + 3, 1, 1); stageHT(T + 3, 0, 0);
        __builtin_amdgcn_s_barrier();
        mfma16(1, 0, Bf0);
        if (it < 7) { asm volatile("s_waitcnt vmcnt(6)" ::: "memory"); }
        __builtin_amdgcn_s_barrier();
    }

#pragma unroll
    for (int fm = 0; fm < 8; ++fm) {
#pragma unroll
        for (int fn = 0; fn < 4; ++fn) {
            int n_g = n0 + wn * 64 + fn * 16 + l15;
            int which = n_g >> 10;
            int h = (n_g >> 6) & 15;
            int d = n_g & 63;
            int m_base = m0 + wm * 128 + fm * 16 + q16 * 4;
            int b = m_base >> 11;
            int nn0 = m_base & 2047;
            if (which == 2) {
                uint2 pk;
                pk.x = pack2bf(acc[fm][fn][0], acc[fm][fn][1]);
                pk.y = pack2bf(acc[fm][fn][2], acc[fm][fn][3]);
                *(uint2*)(vt + ((size_t)((b * H_ + h) * D_ + d) << 11) + nn0) = pk;
            } else {
                size_t base = ((size_t)((b * H_ + h) * N_ + nn0) << 6) + d;
#pragma unroll
                for (int r = 0; r < 4; ++r) {
                    float v = acc[fm][fn][r];
                    if (which == 0) qo[base + (size_t)r * D_] = f2bf(v * QSCALE);
                    else            ko[base + (size_t)r * D_] = f2bf(v);
                }
            }
        }
    }
}

// ---------------- gemm1: out = A * B^T + bias, 64x64 tiles, 4 blocks/CU (r15) -------------
__global__ __launch_bounds__(256, 4) void gemm_out(
    const u16* __restrict__ A, const u16* __restrict__ Bm,
    const float* __restrict__ bias, float* __restrict__ out) {
    __shared__ u16 As[64 * 64];  // 8 KB
    __shared__ u16 Bs[64 * 64];  // 8 KB
    const int K = C_, Ncols = C_, ntiles_n = 16;
    const int tid = threadIdx.x, lane = tid & 63, w = tid >> 6;  // 4 waves
    const int cpx = gridDim.x >> 3;  // 128
    const int sbid = (blockIdx.x & 7) * cpx + (blockIdx.x >> 3);
    const int bx = sbid % ntiles_n, by = sbid / ntiles_n;
    const int m0 = by * 64, n0 = bx * 64;
    const int wm = w >> 1, wn = w & 1;
    const int q16 = lane >> 4, l15 = lane & 15;
    const int r0 = lane >> 3, c0 = (lane & 7) * 8;
    f32x4 acc[2][2] = {};

    for (int k0 = 0; k0 < K; k0 += 64) {
#pragma unroll
        for (int i = 0; i < 2; ++i) {
            int blk = w * 2 + i;   // 0..7: A chunks (8 rows x 128B each)
            int r = blk * 8 + r0;
            async_copy16(A + (size_t)(m0 + r) * K + k0 + c0, (char*)As + blk * 1024);
            async_copy16(Bm + (size_t)(n0 + r) * K + k0 + c0, (char*)Bs + blk * 1024);
        }
        __builtin_amdgcn_s_waitcnt(0);
        __syncthreads();
#pragma unroll
        for (int ks = 0; ks < 2; ++ks) {
            bf16x8 af[2], bf[2];
#pragma unroll
            for (int i = 0; i < 2; ++i) {
                af[i] = *(const bf16x8*)&As[(wm * 32 + i * 16 + l15) * 64 + ks * 32 + q16 * 8];
                bf[i] = *(const bf16x8*)&Bs[(wn * 32 + i * 16 + l15) * 64 + ks * 32 + q16 * 8];
            }
            __builtin_amdgcn_s_setprio(1);
#pragma unroll
            for (int mi = 0; mi < 2; ++mi)
#pragma unroll
                for (int ni = 0; ni < 2; ++ni)
                    acc[mi][ni] = __builtin_amdgcn_mfma_f32_16x16x32_bf16(af[mi], bf[ni], acc[mi][ni], 0, 0, 0);
            __builtin_amdgcn_s_setprio(0);
        }
        __syncthreads();
    }

#pragma unroll
    for (int mi = 0; mi < 2; ++mi) {
#pragma unroll
        for (int ni = 0; ni < 2; ++ni) {
            int n_g = n0 + wn * 32 + ni * 16 + l15;
#pragma unroll
            for (int r = 0; r < 4; ++r) {
                int m_g = m0 + wm * 32 + mi * 16 + q16 * 4 + r;
                out[(size_t)m_g * Ncols + n_g] = acc[mi][ni][r] + bias[n_g];
            }
        }
    }
}

// ---------------- attention: r5 math + TRANSPOSED-GRANULE LDS (conflict-free) -------------
// 32x32 MFMA, in-register P, 8 waves x 32 q, grid 256, XCD-swizzled.
// r16 change: K/V subtiles stored as 8 granule-blocks [g][idx][16B] (g = d-slice for K,
// key-slice for V). Every kf/vf read then has a WAVE-UNIFORM granule (kf: g=ds*2+hi;
// vf0: g=kb2*4+hi; vf1: g=kb2*4+2+hi) and per-lane addr g*1KB + idx*16B -> 64 lanes
// stride 16B across 2KB = zero bank conflicts (was inherent 4-way: 128B rows wrap the
// 32 banks exactly, 32 lanes / 8 granules). Stage: wave w loads granule-block w per
// subtile per array (same 4 copies/wave; per-lane global source, linear LDS dest).
// QK C-layout (m74/m101): col=lane&31=q, row=key=(reg&3)+8*(reg>>2)+4*hi.
__global__ __launch_bounds__(512, 1) void attn_kernel(
    const u16* __restrict__ Q, const u16* __restrict__ K,
    const u16* __restrict__ VT, u16* __restrict__ O) {
    __shared__ u16 Ks[2][2][64 * 64];  // [buf][sub][granule g=d/8][key][8]
    __shared__ u16 Vs[2][2][64 * 64];  // [buf][sub][granule g=key/8][d][8]
    const int tid = threadIdx.x, lane = tid & 63, w = tid >> 6;
    const int l31 = lane & 31, hi = lane >> 5;
    const int bid = blockIdx.x;
    const int bh = (bid & 7) * 4 + (bid >> 6);
    const int q0 = ((bid >> 3) & 7) * 256;
    const size_t head = (size_t)bh * N_ * D_;

    auto stage = [&](int kt, int buf) {
        int key0 = kt * 128;
#pragma unroll
        for (int s = 0; s < 2; ++s) {
            // K granule-block w: lane=key (64), d-slice w*8..w*8+7 -> 16B/lane
            async_copy16(K + head + (size_t)(key0 + s * 64 + lane) * D_ + w * 8,
                         (char*)Ks[buf][s] + w * 1024);
            // V granule-block w: lane=d (64), key-slice key0+s*64+w*8.. +8 -> 16B/lane
            async_copy16(VT + head + (size_t)lane * N_ + key0 + s * 64 + w * 8,
                         (char*)Vs[buf][s] + w * 1024);
        }
    };

    bf16x8 qf[4];
#pragma unroll
    for (int ds = 0; ds < 4; ++ds)
        qf[ds] = *(const bf16x8*)(Q + head + (size_t)(q0 + w * 32 + l31) * D_ + ds * 16 + hi * 8);
    stage(0, 0);
    __builtin_amdgcn_s_waitcnt(0);
    __syncthreads();

    f32x16 o_acc[2] = {};
    float rs = 0.f;

    for (int kt = 0; kt < 16; ++kt) {
        int buf = kt & 1;
        stage((kt + 1) & 15, buf ^ 1);

#pragma unroll
        for (int s = 0; s < 2; ++s) {
#pragma unroll
            for (int kb2 = 0; kb2 < 2; ++kb2) {
                // QK: kf granule g = ds*2+hi (wave-uniform per hi-half), idx = key
                f32x16 st = {};
                __builtin_amdgcn_s_setprio(1);
#pragma unroll
                for (int ds = 0; ds < 4; ++ds) {
                    bf16x8 kf = *(const bf16x8*)&Ks[buf][s][(ds * 2 + hi) * 512 + (kb2 * 32 + l31) * 8];
                    st = __builtin_amdgcn_mfma_f32_32x32x16_bf16(kf, qf[ds], st, 0, 0, 0);
                }
                __builtin_amdgcn_s_setprio(0);

                float p[16];
#pragma unroll
                for (int i = 0; i < 16; ++i) p[i] = EXP2R(st[i]);
#pragma unroll
                for (int i = 0; i < 16; ++i) rs += p[i];

                unsigned a0 = cvtpk2bf(p[0], p[1]),   b0 = cvtpk2bf(p[4], p[5]);
                unsigned a1 = cvtpk2bf(p[2], p[3]),   b1 = cvtpk2bf(p[6], p[7]);
                unsigned a2 = cvtpk2bf(p[8], p[9]),   b2 = cvtpk2bf(p[12], p[13]);
                unsigned a3 = cvtpk2bf(p[10], p[11]), b3 = cvtpk2bf(p[14], p[15]);
                asm("v_permlane32_swap_b32 %0, %1" : "+v"(a0), "+v"(b0));
                asm("v_permlane32_swap_b32 %0, %1" : "+v"(a1), "+v"(b1));
                asm("v_permlane32_swap_b32 %0, %1" : "+v"(a2), "+v"(b2));
                asm("v_permlane32_swap_b32 %0, %1" : "+v"(a3), "+v"(b3));
                union { u32x4 u; bf16x8 v; } af0, af1;
                af0.u = (u32x4){a0, a1, b0, b1};  // keys kb2*32 + 0..15
                af1.u = (u32x4){a2, a3, b2, b3};  // keys kb2*32 + 16..31

                // PV: vf granule g = kb2*4+hi / kb2*4+2+hi (wave-uniform per hi), idx = d
                __builtin_amdgcn_s_setprio(1);
#pragma unroll
                for (int db = 0; db < 2; ++db) {
                    bf16x8 vf0 = *(const bf16x8*)&Vs[buf][s][(kb2 * 4 + hi) * 512 + (db * 32 + l31) * 8];
                    o_acc[db] = __builtin_amdgcn_mfma_f32_32x32x16_bf16(af0.v, vf0, o_acc[db], 0, 0, 0);
                    bf16x8 vf1 = *(const bf16x8*)&Vs[buf][s][(kb2 * 4 + 2 + hi) * 512 + (db * 32 + l31) * 8];
                    o_acc[db] = __builtin_amdgcn_mfma_f32_32x32x16_bf16(af1.v, vf1, o_acc[db], 0, 0, 0);
                }
                __builtin_amdgcn_s_setprio(0);
            }
        }

        __builtin_amdgcn_s_waitcnt(0);
        __syncthreads();
    }

    rs += __shfl_xor(rs, 32);
    float rsi = 1.0f / rs;

    const int b = bh >> 4, h = bh & 15;
#pragma unroll
    for (int reg = 0; reg < 16; ++reg) {
        int qrow = (reg & 3) + 8 * (reg >> 2) + 4 * hi;
        float inv = __shfl(rsi, qrow);
        int qg = q0 + w * 32 + qrow;
#pragma unroll
        for (int db = 0; db < 2; ++db) {
            int d = db * 32 + l31;
            O[((size_t)(b * N_ + qg) << 10) + h * 64 + d] = f2bf(o_acc[db][reg] * inv);
        }
    }
}

extern "C" void kernel_launch(void* const* d_in, const int* in_sizes, int n_in,
                              void* d_out, int out_size, void* d_ws, size_t ws_size,
                              hipStream_t stream) {
    const float* x      = (const float*)d_in[0];
    const float* w_qkv  = (const float*)d_in[1];
    const float* w_proj = (const float*)d_in[2];
    const float* b_proj = (const float*)d_in[3];
    float* out = (float*)d_out;

    char* ws = (char*)d_ws;
    const size_t MB = 1024 * 1024;
    u16* x_bf     = (u16*)(ws + 0 * MB);   // 8 MB
    u16* wqkv_bf  = (u16*)(ws + 8 * MB);   // 6 MB
    u16* wproj_bf = (u16*)(ws + 14 * MB);  // 2 MB
    u16* q_bf     = (u16*)(ws + 16 * MB);  // 8 MB [B,H,N,D]
    u16* k_bf     = (u16*)(ws + 24 * MB);  // 8 MB [B,H,N,D]
    u16* vt_bf    = (u16*)(ws + 32 * MB);  // 8 MB [B,H,D,N]
    u16* ao_bf    = (u16*)(ws + 40 * MB);  // 8 MB [B,N,C]

    cast3_kernel<<<8192, 256, 0, stream>>>(x, w_qkv, w_proj, x_bf, wqkv_bf, wproj_bf);

    gemm_qkv8<<<192, 512, 0, stream>>>(x_bf, wqkv_bf, q_bf, k_bf, vt_bf);

    attn_kernel<<<256, 512, 0, stream>>>(q_bf, k_bf, vt_bf, ao_bf);

    gemm_out<<<64 * 16, 256, 0, stream>>>(ao_bf, wproj_bf, b_proj, out);
}

// Round 17
// 174.256 us; speedup vs baseline: 1.0599x; 1.0599x over previous
//
#include <hip/hip_runtime.h>

typedef unsigned short u16;
typedef __attribute__((ext_vector_type(8))) short bf16x8;
typedef __attribute__((ext_vector_type(4))) float f32x4;
typedef __attribute__((ext_vector_type(16))) float f32x16;
typedef __attribute__((ext_vector_type(4))) unsigned u32x4;

#define B_ 2
#define N_ 2048
#define C_ 1024
#define H_ 16
#define D_ 64
#define M_ (B_ * N_)  // 4096

// 0.125 * log2(e): fold the 1/sqrt(D) scale and exp->exp2 conversion into Q.
#define QSCALE 0.18033688011114336f

#define EXP2R(x) __builtin_amdgcn_exp2f(x)

__device__ __forceinline__ u16 f2bf(float f) {
    union { float f; unsigned u; } x; x.f = f;
    return (u16)((x.u + 0x8000u) >> 16);
}
__device__ __forceinline__ unsigned pack2bf(float a, float b) {
    union { float f; unsigned u; } x, y; x.f = a; y.f = b;
    return __builtin_amdgcn_perm(y.u + 0x8000u, x.u + 0x8000u, 0x07060302);
}
// single-op pack (RTNE), verified correct in r6
__device__ __forceinline__ unsigned cvtpk2bf(float a, float b) {
    unsigned r;
    asm("v_cvt_pk_bf16_f32 %0, %1, %2" : "=v"(r) : "v"(a), "v"(b));
    return r;
}

__device__ __forceinline__ void async_copy16(const void* gsrc, void* ldst) {
    __builtin_amdgcn_global_load_lds(
        (__attribute__((address_space(1))) void*)gsrc,
        (__attribute__((address_space(3))) void*)ldst,
        16, 0, 0);
}

// ---------------- fused cast fp32 -> bf16 (x, w_qkv, w_proj in one launch) ----------------
__global__ void cast3_kernel(const float* __restrict__ x, const float* __restrict__ wq,
                             const float* __restrict__ wp, u16* __restrict__ xo,
                             u16* __restrict__ wqo, u16* __restrict__ wpo) {
    int b = blockIdx.x;
    const float* s; u16* d;
    if (b < 4096)      { s = x;  d = xo;  }
    else if (b < 7168) { s = wq; d = wqo; b -= 4096; }
    else               { s = wp; d = wpo; b -= 7168; }
    int i = (b * 256 + threadIdx.x) * 4;
    const float4 v = *(const float4*)(s + i);
    uint2 o;
    o.x = pack2bf(v.x, v.y);
    o.y = pack2bf(v.z, v.w);
    *(uint2*)(d + i) = o;
}

// ---------------- gemm0: 8-phase 256x256 schedule (r11, verified WAR-safe) ----------------
// C = A(x_bf [4096,1024]) * B(wqkv_bf [3072,1024])^T, scatter epilogue into q/k/vt.
// grid 192 (16x12), 512 thr (8 waves, 2M x 4N), LDS 128 KB = 2 regions x 4 half-tile slots
// {Ah0,Ah1,Bh0,Bh1} of [128][64] bf16, XOR-swizzled (source (lc7^lr3), read ^l7).
// Ledger: A slots read in ph1+ph3 -> Ah0 stages at ph4/ph8; B slots read ph1+ph2 -> Bh0 at
// ph3/ph7, Bh1 at ph4/ph8. vmcnt(6) at ph4/ph8 completes the next tile before its reads.
__global__ __launch_bounds__(512, 2) void gemm_qkv8(
    const u16* __restrict__ A, const u16* __restrict__ Bm,
    u16* __restrict__ qo, u16* __restrict__ ko, u16* __restrict__ vt) {
    __shared__ u16 L[2][4][8192];  // [region][slot][128*64]
    const int tid = threadIdx.x, lane = tid & 63, w = tid >> 6;  // 8 waves
    const int wm = w >> 2, wn = w & 3;
    const int q16 = lane >> 4, l15 = lane & 15, l7 = lane & 7;
    const int lr3 = lane >> 3, lc7 = lane & 7;
    const int sbid = (blockIdx.x & 7) * 24 + (blockIdx.x >> 3);  // XCD swizzle (192%8==0)
    const int bx = sbid % 12, by = sbid / 12;
    const int m0 = by * 256, n0 = bx * 256;
    const int cswz8 = (lc7 ^ lr3) * 8;

    auto stageHT = [&](int t, int isB, int h) {  // one 16KB half-tile, 2 loads/thread
        if (t > 15) return;
        const u16* src = isB ? Bm : A;
        int base_row = (isB ? n0 : m0) + h * 128;
#pragma unroll
        for (int i = 0; i < 2; ++i) {
            int c = w * 2 + i;  // 1KB chunk 0..15 (8 rows x 128B)
            async_copy16(src + (size_t)(base_row + c * 8 + lr3) * 1024 + t * 64 + cswz8,
                         (char*)L + ((t & 1) * 4 + isB * 2 + h) * 16384 + c * 1024);
        }
    };

    // prologue: tile0 (4 halves) + tile1 (3 halves); drain to 3 HT; barrier.
    stageHT(0, 0, 0); stageHT(0, 1, 0); stageHT(0, 1, 1); stageHT(0, 0, 1);
    stageHT(1, 0, 0); stageHT(1, 1, 0); stageHT(1, 1, 1);
    asm volatile("s_waitcnt vmcnt(6)" ::: "memory");
    __builtin_amdgcn_s_barrier();

    f32x4 acc[8][4] = {};
    const int aRow = l15 * 64;
    const int colsw0 = (q16 ^ l7) * 8, colsw1 = ((4 + q16) ^ l7) * 8;
    const u16* LA[2] = { &L[0][wm][0], &L[1][wm][0] };
    const u16* LB[2] = { &L[0][2 + (wn >> 1)][0], &L[1][2 + (wn >> 1)][0] };
    const int bOff = (wn & 1) * 4096;

    bf16x8 Af[4][2], Bf0[2][2], Bf1[2][2];

    auto readA = [&](int P, int mh) {
#pragma unroll
        for (int i = 0; i < 4; ++i) {
            Af[i][0] = *(const bf16x8*)(LA[P] + (mh * 64 + i * 16) * 64 + aRow + colsw0);
            Af[i][1] = *(const bf16x8*)(LA[P] + (mh * 64 + i * 16) * 64 + aRow + colsw1);
        }
    };
    auto readB = [&](int P, int nh, bf16x8 (*Bf)[2]) {
#pragma unroll
        for (int j = 0; j < 2; ++j) {
            Bf[j][0] = *(const bf16x8*)(LB[P] + bOff + (nh * 32 + j * 16) * 64 + aRow + colsw0);
            Bf[j][1] = *(const bf16x8*)(LB[P] + bOff + (nh * 32 + j * 16) * 64 + aRow + colsw1);
        }
    };
    auto mfma16 = [&](int mh, int nh, bf16x8 (*Bf)[2]) {
        __builtin_amdgcn_s_setprio(1);
#pragma unroll
        for (int i = 0; i < 4; ++i)
#pragma unroll
            for (int j = 0; j < 2; ++j)
#pragma unroll
                for (int ks = 0; ks < 2; ++ks)
                    acc[mh * 4 + i][nh * 2 + j] = __builtin_amdgcn_mfma_f32_16x16x32_bf16(
                        Af[i][ks], Bf[j][ks], acc[mh * 4 + i][nh * 2 + j], 0, 0, 0);
        __builtin_amdgcn_s_setprio(0);
    };

    for (int it = 0; it < 8; ++it) {
        const int T = 2 * it;
        readA(0, 0); readB(0, 0, Bf0); stageHT(T + 1, 0, 1);
        __builtin_amdgcn_s_barrier();
        mfma16(0, 0, Bf0);
        __builtin_amdgcn_s_barrier();
        readB(0, 1, Bf1);
        __builtin_amdgcn_s_barrier();
        mfma16(0, 1, Bf1);
        __builtin_amdgcn_s_barrier();
        readA(0, 1); stageHT(T + 2, 1, 0);
        __builtin_amdgcn_s_barrier();
        mfma16(1, 1, Bf1);
        __builtin_amdgcn_s_barrier();
        stageHT(T + 2, 1, 1); stageHT(T + 2, 0, 0);
        __builtin_amdgcn_s_barrier();
        mfma16(1, 0, Bf0);
        if (it < 7) { asm volatile("s_waitcnt vmcnt(6)" ::: "memory"); }
        else        { asm volatile("s_waitcnt vmcnt(0)" ::: "memory"); }
        __builtin_amdgcn_s_barrier();
        readA(1, 0); readB(1, 0, Bf0); stageHT(T + 2, 0, 1);
        __builtin_amdgcn_s_barrier();
        mfma16(0, 0, Bf0);
        __builtin_amdgcn_s_barrier();
        readB(1, 1, Bf1);
        __builtin_amdgcn_s_barrier();
        mfma16(0, 1, Bf1);
        __builtin_amdgcn_s_barrier();
        readA(1, 1); stageHT(T + 3, 1, 0);
        __builtin_amdgcn_s_barrier();
        mfma16(1, 1, Bf1);
        __builtin_amdgcn_s_barrier();
        stageHT(T + 3, 1, 1); stageHT(T + 3, 0, 0);
        __builtin_amdgcn_s_barrier();
        mfma16(1, 0, Bf0);
        if (it < 7) { asm volatile("s_waitcnt vmcnt(6)" ::: "memory"); }
        __builtin_amdgcn_s_barrier();
    }

#pragma unroll
    for (int fm = 0; fm < 8; ++fm) {
#pragma unroll
        for (int fn = 0; fn < 4; ++fn) {
            int n_g = n0 + wn * 64 + fn * 16 + l15;
            int which = n_g >> 10;
            int h = (n_g >> 6) & 15;
            int d = n_g & 63;
            int m_base = m0 + wm * 128 + fm * 16 + q16 * 4;
            int b = m_base >> 11;
            int nn0 = m_base & 2047;
            if (which == 2) {
                uint2 pk;
                pk.x = pack2bf(acc[fm][fn][0], acc[fm][fn][1]);
                pk.y = pack2bf(acc[fm][fn][2], acc[fm][fn][3]);
                *(uint2*)(vt + ((size_t)((b * H_ + h) * D_ + d) << 11) + nn0) = pk;
            } else {
                size_t base = ((size_t)((b * H_ + h) * N_ + nn0) << 6) + d;
#pragma unroll
                for (int r = 0; r < 4; ++r) {
                    float v = acc[fm][fn][r];
                    if (which == 0) qo[base + (size_t)r * D_] = f2bf(v * QSCALE);
                    else            ko[base + (size_t)r * D_] = f2bf(v);
                }
            }
        }
    }
}

// ---------------- gemm1: out = A * B^T + bias, 64x64 tiles, 4 blocks/CU (r15) -------------
__global__ __launch_bounds__(256, 4) void gemm_out(
    const u16* __restrict__ A, const u16* __restrict__ Bm,
    const float* __restrict__ bias, float* __restrict__ out) {
    __shared__ u16 As[64 * 64];  // 8 KB
    __shared__ u16 Bs[64 * 64];  // 8 KB
    const int K = C_, Ncols = C_, ntiles_n = 16;
    const int tid = threadIdx.x, lane = tid & 63, w = tid >> 6;  // 4 waves
    const int cpx = gridDim.x >> 3;  // 128
    const int sbid = (blockIdx.x & 7) * cpx + (blockIdx.x >> 3);
    const int bx = sbid % ntiles_n, by = sbid / ntiles_n;
    const int m0 = by * 64, n0 = bx * 64;
    const int wm = w >> 1, wn = w & 1;
    const int q16 = lane >> 4, l15 = lane & 15;
    const int r0 = lane >> 3, c0 = (lane & 7) * 8;
    f32x4 acc[2][2] = {};

    for (int k0 = 0; k0 < K; k0 += 64) {
#pragma unroll
        for (int i = 0; i < 2; ++i) {
            int blk = w * 2 + i;   // 0..7: A chunks (8 rows x 128B each)
            int r = blk * 8 + r0;
            async_copy16(A + (size_t)(m0 + r) * K + k0 + c0, (char*)As + blk * 1024);
            async_copy16(Bm + (size_t)(n0 + r) * K + k0 + c0, (char*)Bs + blk * 1024);
        }
        __builtin_amdgcn_s_waitcnt(0);
        __syncthreads();
#pragma unroll
        for (int ks = 0; ks < 2; ++ks) {
            bf16x8 af[2], bf[2];
#pragma unroll
            for (int i = 0; i < 2; ++i) {
                af[i] = *(const bf16x8*)&As[(wm * 32 + i * 16 + l15) * 64 + ks * 32 + q16 * 8];
                bf[i] = *(const bf16x8*)&Bs[(wn * 32 + i * 16 + l15) * 64 + ks * 32 + q16 * 8];
            }
            __builtin_amdgcn_s_setprio(1);
#pragma unroll
            for (int mi = 0; mi < 2; ++mi)
#pragma unroll
                for (int ni = 0; ni < 2; ++ni)
                    acc[mi][ni] = __builtin_amdgcn_mfma_f32_16x16x32_bf16(af[mi], bf[ni], acc[mi][ni], 0, 0, 0);
            __builtin_amdgcn_s_setprio(0);
        }
        __syncthreads();
    }

#pragma unroll
    for (int mi = 0; mi < 2; ++mi) {
#pragma unroll
        for (int ni = 0; ni < 2; ++ni) {
            int n_g = n0 + wn * 32 + ni * 16 + l15;
#pragma unroll
            for (int r = 0; r < 4; ++r) {
                int m_g = m0 + wm * 32 + mi * 16 + q16 * 4 + r;
                out[(size_t)m_g * Ncols + n_g] = acc[mi][ni][r] + bias[n_g];
            }
        }
    }
}

// ---------------- attention: granule LDS + register-staged coalesced writes ----------------
// r17: r16 proved the granule layout kills all bank conflicts (4.2M -> 0) but global_load_lds
// forced a scattered global source (slower net). Now: stage via REGISTERS -- coalesced
// global_load_dwordx4 (identical source pattern to the proven r15 staging) issued at the
// TOP of each kt (hidden under compute), then ds_write_b128 into the granule layout after
// compute. Write idx XOR lc7 makes writes bank-uniform; reads use the same XOR (wave-
// uniform per granule -> address set unchanged -> stays conflict-free, measured r16).
// K: [g=d/8][idx=key^g][8];  V: [g=key/8][idx=d^g][8] per 64x64 subtile.
// QK C-layout (m74/m101): col=lane&31=q, row=key=(reg&3)+8*(reg>>2)+4*hi.
__global__ __launch_bounds__(512, 1) void attn_kernel(
    const u16* __restrict__ Q, const u16* __restrict__ K,
    const u16* __restrict__ VT, u16* __restrict__ O) {
    __shared__ u16 Ks[2][2][64 * 64];  // [buf][sub][g][idx^g][8]
    __shared__ u16 Vs[2][2][64 * 64];
    const int tid = threadIdx.x, lane = tid & 63, w = tid >> 6;  // 8 waves
    const int l31 = lane & 31, hi = lane >> 5;
    const int lr3 = lane >> 3, lc7 = lane & 7;
    const int bid = blockIdx.x;
    const int bh = (bid & 7) * 4 + (bid >> 6);
    const int q0 = ((bid >> 3) & 7) * 256;
    const size_t head = (size_t)bh * N_ * D_;
    const int row8 = w * 8 + lr3;                 // this thread's row within a 64-subtile
    const int widx = ((row8 ^ lc7) * 8);          // swizzled write idx (u16 units)

    bf16x8 stK[2], stV[2];  // in-flight staging registers

    // coalesced loads (same global pattern as the proven r15 staging)
    auto issue = [&](int kt) {
        int key0 = kt * 128;
#pragma unroll
        for (int s = 0; s < 2; ++s) {
            stK[s] = *(const bf16x8*)(K + head + (size_t)(key0 + s * 64 + row8) * D_ + lc7 * 8);
            stV[s] = *(const bf16x8*)(VT + head + (size_t)row8 * N_ + key0 + s * 64 + lc7 * 8);
        }
    };
    // bank-uniform granule writes (compiler inserts the vmcnt wait on stK/stV use)
    auto commit = [&](int buf) {
#pragma unroll
        for (int s = 0; s < 2; ++s) {
            *(bf16x8*)&Ks[buf][s][lc7 * 512 + widx] = stK[s];
            *(bf16x8*)&Vs[buf][s][lc7 * 512 + widx] = stV[s];
        }
    };

    bf16x8 qf[4];
#pragma unroll
    for (int ds = 0; ds < 4; ++ds)
        qf[ds] = *(const bf16x8*)(Q + head + (size_t)(q0 + w * 32 + l31) * D_ + ds * 16 + hi * 8);
    issue(0);
    commit(0);
    __syncthreads();

    f32x16 o_acc[2] = {};
    float rs = 0.f;

    for (int kt = 0; kt < 16; ++kt) {
        int buf = kt & 1;
        issue((kt + 1) & 15);  // loads in flight for the whole compute phase

#pragma unroll
        for (int s = 0; s < 2; ++s) {
#pragma unroll
            for (int kb2 = 0; kb2 < 2; ++kb2) {
                // QK: kf granule g = ds*2+hi, idx = (kb2*32+l31) ^ g
                f32x16 st = {};
                __builtin_amdgcn_s_setprio(1);
#pragma unroll
                for (int ds = 0; ds < 4; ++ds) {
                    int g = ds * 2 + hi;
                    bf16x8 kf = *(const bf16x8*)&Ks[buf][s][g * 512 + ((kb2 * 32 + l31) ^ g) * 8];
                    st = __builtin_amdgcn_mfma_f32_32x32x16_bf16(kf, qf[ds], st, 0, 0, 0);
                }
                __builtin_amdgcn_s_setprio(0);

                float p[16];
#pragma unroll
                for (int i = 0; i < 16; ++i) p[i] = EXP2R(st[i]);
#pragma unroll
                for (int i = 0; i < 16; ++i) rs += p[i];

                unsigned a0 = cvtpk2bf(p[0], p[1]),   b0 = cvtpk2bf(p[4], p[5]);
                unsigned a1 = cvtpk2bf(p[2], p[3]),   b1 = cvtpk2bf(p[6], p[7]);
                unsigned a2 = cvtpk2bf(p[8], p[9]),   b2 = cvtpk2bf(p[12], p[13]);
                unsigned a3 = cvtpk2bf(p[10], p[11]), b3 = cvtpk2bf(p[14], p[15]);
                asm("v_permlane32_swap_b32 %0, %1" : "+v"(a0), "+v"(b0));
                asm("v_permlane32_swap_b32 %0, %1" : "+v"(a1), "+v"(b1));
                asm("v_permlane32_swap_b32 %0, %1" : "+v"(a2), "+v"(b2));
                asm("v_permlane32_swap_b32 %0, %1" : "+v"(a3), "+v"(b3));
                union { u32x4 u; bf16x8 v; } af0, af1;
                af0.u = (u32x4){a0, a1, b0, b1};  // keys kb2*32 + 0..15
                af1.u = (u32x4){a2, a3, b2, b3};  // keys kb2*32 + 16..31

                // PV: vf granule g = kb2*4+hi / kb2*4+2+hi, idx = (db*32+l31) ^ g
                __builtin_amdgcn_s_setprio(1);
#pragma unroll
                for (int db = 0; db < 2; ++db) {
                    int g0 = kb2 * 4 + hi, g1 = kb2 * 4 + 2 + hi;
                    bf16x8 vf0 = *(const bf16x8*)&Vs[buf][s][g0 * 512 + ((db * 32 + l31) ^ g0) * 8];
                    o_acc[db] = __builtin_amdgcn_mfma_f32_32x32x16_bf16(af0.v, vf0, o_acc[db], 0, 0, 0);
                    bf16x8 vf1 = *(const bf16x8*)&Vs[buf][s][g1 * 512 + ((db * 32 + l31) ^ g1) * 8];
                    o_acc[db] = __builtin_amdgcn_mfma_f32_32x32x16_bf16(af1.v, vf1, o_acc[db], 0, 0, 0);
                }
                __builtin_amdgcn_s_setprio(0);
            }
        }

        // staged loads have landed (compiler waits on stK/stV); write next tile's buffer.
        // buf^1 was last read in kt-1; the kt-1 end barrier makes this WAR-safe.
        commit(buf ^ 1);
        __syncthreads();
    }

    rs += __shfl_xor(rs, 32);
    float rsi = 1.0f / rs;

    const int b = bh >> 4, h = bh & 15;
#pragma unroll
    for (int reg = 0; reg < 16; ++reg) {
        int qrow = (reg & 3) + 8 * (reg >> 2) + 4 * hi;
        float inv = __shfl(rsi, qrow);
        int qg = q0 + w * 32 + qrow;
#pragma unroll
        for (int db = 0; db < 2; ++db) {
            int d = db * 32 + l31;
            O[((size_t)(b * N_ + qg) << 10) + h * 64 + d] = f2bf(o_acc[db][reg] * inv);
        }
    }
}

extern "C" void kernel_launch(void* const* d_in, const int* in_sizes, int n_in,
                              void* d_out, int out_size, void* d_ws, size_t ws_size,
                              hipStream_t stream) {
    const float* x      = (const float*)d_in[0];
    const float* w_qkv  = (const float*)d_in[1];
    const float* w_proj = (const float*)d_in[2];
    const float* b_proj = (const float*)d_in[3];
    float* out = (float*)d_out;

    char* ws = (char*)d_ws;
    const size_t MB = 1024 * 1024;
    u16* x_bf     = (u16*)(ws + 0 * MB);   // 8 MB
    u16* wqkv_bf  = (u16*)(ws + 8 * MB);   // 6 MB
    u16* wproj_bf = (u16*)(ws + 14 * MB);  // 2 MB
    u16* q_bf     = (u16*)(ws + 16 * MB);  // 8 MB [B,H,N,D]
    u16* k_bf     = (u16*)(ws + 24 * MB);  // 8 MB [B,H,N,D]
    u16* vt_bf    = (u16*)(ws + 32 * MB);  // 8 MB [B,H,D,N]
    u16* ao_bf    = (u16*)(ws + 40 * MB);  // 8 MB [B,N,C]

    cast3_kernel<<<8192, 256, 0, stream>>>(x, w_qkv, w_proj, x_bf, wqkv_bf, wproj_bf);

    gemm_qkv8<<<192, 512, 0, stream>>>(x_bf, wqkv_bf, q_bf, k_bf, vt_bf);

    attn_kernel<<<256, 512, 0, stream>>>(q_bf, k_bf, vt_bf, ao_bf);

    gemm_out<<<64 * 16, 256, 0, stream>>>(ao_bf, wproj_bf, b_proj, out);
}